// Round 15
// baseline (1872.016 us; speedup 1.0000x reference)
//
#include <hip/hip_runtime.h>
#include <math.h>

typedef _Float16 f16;
typedef _Float16 f16x8 __attribute__((ext_vector_type(8)));
typedef _Float16 f16x4 __attribute__((ext_vector_type(4)));
typedef float    f32x4 __attribute__((ext_vector_type(4)));

#define BATCH 256
#define SEQ   1024
#define DI    128
#define DH    128
#define DM    144
#define MR    16
#define SXS   132   // f16 panel stride (4*66 dw = 8 mod 32)
#define SYS   164   // f16 stride, 160-col panels
#define SZS   134   // f32 stride (fallback only)
#define PGS   20    // (fallback only)
#define NW    400   // xproj cols: r 0-127, z 128-255, mlp0 256-399
#define WS_ELEMS ((size_t)16 * SEQ * NW * 16)

#define MFMA16(a, b, c) __builtin_amdgcn_mfma_f32_16x16x32_f16((a), (b), (c), 0, 0, 0)

// rcp-based activations (v_rcp_f32; ~1e-6 rel err, inside 1.86e-2 budget)
__device__ __forceinline__ float sigm(float x) {
    return __builtin_amdgcn_rcpf(1.f + __expf(-x));
}
__device__ __forceinline__ float tanh_fast(float x) {
    const float e = __expf(2.f * x);
    return 1.f - 2.f * __builtin_amdgcn_rcpf(e + 1.f);
}
// LDS-only barrier: global loads/stores stay in flight (T4).
__device__ __forceinline__ void bar_lds() {
    asm volatile("s_waitcnt lgkmcnt(0)" ::: "memory");
    __builtin_amdgcn_s_barrier();
}
__device__ __forceinline__ f32x4 cvt4(f16x4 v) {
    f32x4 r; r[0] = (float)v[0]; r[1] = (float)v[1]; r[2] = (float)v[2]; r[3] = (float)v[3];
    return r;
}

// ===================== pre-pass: xproj = x @ [r_w | z_w | h_w0(x-rows)] =====================
__global__ __launch_bounds__(512, 2) void xproj_kernel(
    const float* __restrict__ inputs,
    const float* __restrict__ r_w, const float* __restrict__ z_w,
    const float* __restrict__ h_w0, f16* __restrict__ ws)
{
    __shared__ __align__(16) f16 lx[16 * SXS];

    const int rb = blockIdx.x >> 5;
    const int tc = blockIdx.x & 31;
    const int tid = threadIdx.x;
    const int w   = tid >> 6;
    const int ln  = tid & 15;
    const int kg  = (tid & 63) >> 4;
    const int b0  = rb * MR;

    const int nt = (w == 0) ? 4 : 3;
    f16x8 wb[4][4];
    #pragma unroll
    for (int i = 0; i < 4; ++i) if (i < nt) {
        const int tile = w + 8 * i;
        #pragma unroll
        for (int kt = 0; kt < 4; ++kt) {
            f16x8 f;
            #pragma unroll
            for (int j = 0; j < 8; ++j) {
                const int k = kt * 32 + kg * 8 + j;
                float v;
                if (tile < 8)       v = r_w [(size_t)k * DH + tile * 16 + ln];
                else if (tile < 16) v = z_w [(size_t)k * DH + (tile - 8) * 16 + ln];
                else                v = h_w0[(size_t)k * DM + (tile - 16) * 16 + ln];
                f[j] = (f16)v;
            }
            wb[i][kt] = f;
        }
    }

    for (int tt = 0; tt < 32; ++tt) {
        const int t = tc * 32 + tt;
        if (tid < 256) {
            const int row = tid >> 4, seg = tid & 15;
            const float* xb = inputs + ((size_t)(b0 + row) * SEQ + t) * DI + seg * 8;
            const float4 a = ((const float4*)xb)[0];
            const float4 b = ((const float4*)(xb + 4))[0];
            f16x8 v; v[0]=(f16)a.x; v[1]=(f16)a.y; v[2]=(f16)a.z; v[3]=(f16)a.w;
                     v[4]=(f16)b.x; v[5]=(f16)b.y; v[6]=(f16)b.z; v[7]=(f16)b.w;
            *(f16x8*)(lx + row * SXS + seg * 8) = v;
        }
        __syncthreads();
        f16x8 xa[4];
        #pragma unroll
        for (int kt = 0; kt < 4; ++kt)
            xa[kt] = *(const f16x8*)(lx + ln * SXS + kt * 32 + kg * 8);
        #pragma unroll
        for (int i = 0; i < 4; ++i) if (i < nt) {
            const int tile = w + 8 * i;
            f32x4 a = {0.f, 0.f, 0.f, 0.f};
            #pragma unroll
            for (int kt = 0; kt < 4; ++kt) a = MFMA16(xa[kt], wb[i][kt], a);
            f16x4 o; o[0]=(f16)a[0]; o[1]=(f16)a[1]; o[2]=(f16)a[2]; o[3]=(f16)a[3];
            *(f16x4*)(ws + ((size_t)(rb * SEQ + t) * NW + tile * 16 + ln) * 16 + kg * 4) = o;
        }
        __syncthreads();
    }
}

// ===================== main RNN kernel (R14 champion + s2 reorder + 3-way chains) =====================
__global__ __launch_bounds__(512, 2) __attribute__((amdgpu_waves_per_eu(2, 2)))
void hgru_kernel(
    const f16* __restrict__ ws,
    const float* __restrict__ r_w, const float* __restrict__ r_b,
    const float* __restrict__ z_w, const float* __restrict__ z_b,
    const float* __restrict__ h_w0, const float* __restrict__ h_b0,
    const float* __restrict__ h_w1, const float* __restrict__ h_b1,
    const float* __restrict__ h_w2, const float* __restrict__ h_b2,
    float* __restrict__ out, float* __restrict__ hid_out)
{
    __shared__ __align__(16) f16 sh16[MR * SXS];  // h f16 A-panel
    __shared__ __align__(16) f16 srh[MR * SXS];   // r*h A-panel
    __shared__ __align__(16) f16 sy0[MR * SYS];   // mlp act1 (padded to 160)
    __shared__ __align__(16) f16 sy1[MR * SYS];   // mlp act2

    const int tid  = threadIdx.x;
    const int w    = tid >> 6;      // wave 0..7
    const int lane = tid & 63;
    const int ln   = lane & 15;
    const int kg   = lane >> 4;     // C rows 4*kg..4*kg+3
    const int rb   = blockIdx.x;
    const int b0   = rb * MR;
    const int col  = w * 16 + ln;

    for (int i = tid; i < MR * SYS; i += 512) { sy0[i] = (f16)0.f; sy1[i] = (f16)0.f; }
    for (int i = tid; i < MR * SXS; i += 512) { sh16[i] = (f16)0.f; }

    // ---- register weight fragments (h-rows + MLP interior) ----
    f16x8 wrh[4], wzh[4], w0h[4];
    #pragma unroll
    for (int kt = 0; kt < 4; ++kt) {
        f16x8 a, b, c;
        #pragma unroll
        for (int j = 0; j < 8; ++j) {
            const int k = DI + kt * 32 + kg * 8 + j;
            a[j] = (f16)r_w [(size_t)k * DH + col];
            b[j] = (f16)z_w [(size_t)k * DH + col];
            c[j] = (f16)h_w0[(size_t)k * DM + col];
        }
        wrh[kt] = a; wzh[kt] = b; w0h[kt] = c;
    }
    f16x8 w1f[5], w2f[5];
    #pragma unroll
    for (int kt = 0; kt < 5; ++kt) {
        f16x8 a, b;
        #pragma unroll
        for (int j = 0; j < 8; ++j) {
            const int k = kt * 32 + kg * 8 + j;
            const bool in = (k < DM);
            a[j] = in ? (f16)h_w1[(size_t)k * DM + col] : (f16)0.f;
            b[j] = in ? (f16)h_w2[(size_t)k * DH + col] : (f16)0.f;
        }
        w1f[kt] = a; w2f[kt] = b;
    }
    // ext: w==0 -> y0 tile8 (h-rows of h_w0); w==1 -> y1 tile8 (h_w1)
    f16x8 ext[5];
    #pragma unroll
    for (int kt = 0; kt < 5; ++kt) {
        f16x8 f;
        #pragma unroll
        for (int j = 0; j < 8; ++j) {
            const int k = kt * 32 + kg * 8 + j;
            float v = 0.f;
            if (w == 0 && kt < 4)      v = (float)h_w0[(size_t)(DI + k) * DM + 128 + ln];
            else if (w == 1 && k < DM) v = (float)h_w1[(size_t)k * DM + 128 + ln];
            f[j] = (f16)v;
        }
        ext[kt] = f;
    }

    const float b1r = r_b[col], b1z = z_b[col];
    const float b2  = h_b0[col], b3 = h_b1[col], b4 = h_b2[col];
    const float bext = (w == 0) ? h_b0[128 + ln] : (w == 1) ? h_b1[128 + ln] : 0.f;

    float* op[4];
    #pragma unroll
    for (int j = 0; j < 4; ++j)
        op[j] = out + (size_t)(b0 + 4 * kg + j) * SEQ * DH + col;

    // ---- ws C-in streams ----
    const size_t stepAdv = (size_t)NW * 16;
    const f16* pr = ws + ((size_t)rb * SEQ) * stepAdv + ((size_t)(      col) * 16 + kg * 4);
    const f16* pz = ws + ((size_t)rb * SEQ) * stepAdv + ((size_t)(128 + col) * 16 + kg * 4);
    const f16* pm = ws + ((size_t)rb * SEQ) * stepAdv + ((size_t)(256 + col) * 16 + kg * 4);
    const f16* p8 = ws + ((size_t)rb * SEQ) * stepAdv + ((size_t)(384 + ln ) * 16 + kg * 4);

    f16x4 curR = *(const f16x4*)pr;
    f16x4 curZ = *(const f16x4*)pz;
    f16x4 curM = *(const f16x4*)pm;
    f16x4 cur8 = (w == 0) ? *(const f16x4*)p8 : f16x4{0, 0, 0, 0};

    // per-wave register state: h rows 4kg+j at this wave's col; z gate likewise
    f32x4 hreg = {0.f, 0.f, 0.f, 0.f};
    f32x4 zreg = {0.f, 0.f, 0.f, 0.f};

    bar_lds();

    const f32x4 z4 = {0.f, 0.f, 0.f, 0.f};

    for (int t = 0; t < SEQ; ++t) {
        // ======== s1: issue critical ha ds_reads FIRST ========
        f16x8 ha[4];
        #pragma unroll
        for (int kt = 0; kt < 4; ++kt)
            ha[kt] = *(const f16x8*)(sh16 + ln * SXS + kt * 32 + kg * 8);

        // prefetch next step's C-ins (after ha reads; a full step of cover)
        const size_t nadv = (size_t)((t + 1 < SEQ) ? t + 1 : t) * stepAdv;
        const f16x4 nxtR = *(const f16x4*)(pr + nadv);
        const f16x4 nxtZ = *(const f16x4*)(pz + nadv);
        const f16x4 nxtM = *(const f16x4*)(pm + nadv);
        const f16x4 nxt8 = (w == 0) ? *(const f16x4*)(p8 + nadv) : f16x4{0, 0, 0, 0};

        // r gate (split 2+2 chains); h from registers
        f32x4 r0 = cvt4(curR), r1 = z4;
        r0 = MFMA16(ha[0], wrh[0], r0);
        r1 = MFMA16(ha[1], wrh[1], r1);
        r0 = MFMA16(ha[2], wrh[2], r0);
        r1 = MFMA16(ha[3], wrh[3], r1);
        const f32x4 ar = r0 + r1;
        #pragma unroll
        for (int j = 0; j < 4; ++j) {
            const float g = sigm(ar[j] + b1r);
            srh[(4 * kg + j) * SXS + col] = (f16)(g * hreg[j]);
        }
        bar_lds(); // A

        // ======== s2: ra reads FIRST, z-shadow hides their latency, then y0 ========
        f16x8 ra[4];
        #pragma unroll
        for (int kt = 0; kt < 4; ++kt)
            ra[kt] = *(const f16x8*)(srh + ln * SXS + kt * 32 + kg * 8);

        // z h-part shadow (register-only; overlaps ra ds_read latency)
        f32x4 zc0 = cvt4(curZ), zc1 = z4;
        zc0 = MFMA16(ha[0], wzh[0], zc0);
        zc1 = MFMA16(ha[1], wzh[1], zc1);
        zc0 = MFMA16(ha[2], wzh[2], zc0);
        zc1 = MFMA16(ha[3], wzh[3], zc1);

        // y0 (critical)
        f32x4 m0 = cvt4(curM), m1 = z4;
        m0 = MFMA16(ra[0], w0h[0], m0);
        m1 = MFMA16(ra[1], w0h[1], m1);
        m0 = MFMA16(ra[2], w0h[2], m0);
        m1 = MFMA16(ra[3], w0h[3], m1);
        const f32x4 a0 = m0 + m1;
        #pragma unroll
        for (int j = 0; j < 4; ++j)
            sy0[(4 * kg + j) * SYS + col] = (f16)fmaxf(a0[j] + b2, 0.f);
        if (w == 0) {
            f32x4 e0 = cvt4(cur8), e1 = z4;
            e0 = MFMA16(ra[0], ext[0], e0);
            e1 = MFMA16(ra[1], ext[1], e1);
            e0 = MFMA16(ra[2], ext[2], e0);
            e1 = MFMA16(ra[3], ext[3], e1);
            const f32x4 a8 = e0 + e1;
            #pragma unroll
            for (int j = 0; j < 4; ++j)
                sy0[(4 * kg + j) * SYS + 128 + ln] = (f16)fmaxf(a8[j] + bext, 0.f);
        }
        // z epilogue -> registers (consumed by s4, same wave/lane)
        {
            const f32x4 zc = zc0 + zc1;
            #pragma unroll
            for (int j = 0; j < 4; ++j) zreg[j] = sigm(zc[j] + b1z);
        }
        bar_lds(); // B

        // ======== s3: y1 (3-way chains, dep depth 2) ========
        f16x8 ya[5];
        #pragma unroll
        for (int kt = 0; kt < 5; ++kt)
            ya[kt] = *(const f16x8*)(sy0 + ln * SYS + kt * 32 + kg * 8);
        f32x4 c0 = z4, c1 = z4, c2 = z4;
        c0 = MFMA16(ya[0], w1f[0], c0);
        c1 = MFMA16(ya[1], w1f[1], c1);
        c2 = MFMA16(ya[4], w1f[4], c2);
        c0 = MFMA16(ya[2], w1f[2], c0);
        c1 = MFMA16(ya[3], w1f[3], c1);
        const f32x4 a1 = (c0 + c1) + c2;
        #pragma unroll
        for (int j = 0; j < 4; ++j)
            sy1[(4 * kg + j) * SYS + col] = (f16)fmaxf(a1[j] + b3, 0.f);
        if (w == 1) {
            f32x4 e0 = z4, e1 = z4, e2 = z4;
            e0 = MFMA16(ya[0], ext[0], e0);
            e1 = MFMA16(ya[1], ext[1], e1);
            e2 = MFMA16(ya[4], ext[4], e2);
            e0 = MFMA16(ya[2], ext[2], e0);
            e1 = MFMA16(ya[3], ext[3], e1);
            const f32x4 a8 = (e0 + e1) + e2;
            #pragma unroll
            for (int j = 0; j < 4; ++j)
                sy1[(4 * kg + j) * SYS + 128 + ln] = (f16)fmaxf(a8[j] + bext, 0.f);
        }
        bar_lds(); // C

        // ======== s4: h~ (3-way chains); h update in registers ========
        f16x8 za[5];
        #pragma unroll
        for (int kt = 0; kt < 5; ++kt)
            za[kt] = *(const f16x8*)(sy1 + ln * SYS + kt * 32 + kg * 8);
        f32x4 d0 = z4, d1 = z4, d2 = z4;
        d0 = MFMA16(za[0], w2f[0], d0);
        d1 = MFMA16(za[1], w2f[1], d1);
        d2 = MFMA16(za[4], w2f[4], d2);
        d0 = MFMA16(za[2], w2f[2], d0);
        d1 = MFMA16(za[3], w2f[3], d1);
        const f32x4 hv = (d0 + d1) + d2;
        #pragma unroll
        for (int j = 0; j < 4; ++j) {
            const float ht = tanh_fast(hv[j] + b4);
            const float hn = (1.f - zreg[j]) * hreg[j] + zreg[j] * ht;
            hreg[j] = hn;
            sh16[(4 * kg + j) * SXS + col] = (f16)hn;
            *op[j] = hn; op[j] += DH;   // fire-and-forget, stays in VMEM queue
        }
        bar_lds(); // D

        curR = nxtR; curZ = nxtZ; curM = nxtM; cur8 = nxt8;
    }

    // final hidden state from registers (each lane owns rows 4kg+j at col)
    #pragma unroll
    for (int j = 0; j < 4; ++j)
        hid_out[(size_t)(b0 + 4 * kg + j) * DH + col] = hreg[j];
}

// ===================== fallback (R8 monolithic) if ws too small =====================
__global__ __launch_bounds__(512, 2) __attribute__((amdgpu_waves_per_eu(2, 2)))
void hgru_fallback(
    const float* __restrict__ inputs,
    const float* __restrict__ r_w, const float* __restrict__ r_b,
    const float* __restrict__ z_w, const float* __restrict__ z_b,
    const float* __restrict__ h_w0, const float* __restrict__ h_b0,
    const float* __restrict__ h_w1, const float* __restrict__ h_b1,
    const float* __restrict__ h_w2, const float* __restrict__ h_b2,
    float* __restrict__ out, float* __restrict__ hid_out)
{
    __shared__ __align__(16) f16   sx [MR * SXS];
    __shared__ __align__(16) f16   sh16[MR * SXS];
    __shared__ __align__(16) f16   srh[MR * SXS];
    __shared__ __align__(16) f16   sy0[MR * SYS];
    __shared__ __align__(16) f16   sy1[MR * SYS];
    __shared__ __align__(16) float sz [MR * SZS];
    __shared__ __align__(16) float shf[MR * SZS];
    __shared__ __align__(16) float pg[256 * PGS];
    __shared__ __align__(16) float pm[DM  * PGS];

    const int tid  = threadIdx.x;
    const int w    = tid >> 6;
    const int lane = tid & 63;
    const int ln   = lane & 15;
    const int kg   = lane >> 4;
    const int b0   = blockIdx.x * MR;
    const int col  = w * 16 + ln;

    for (int i = tid; i < MR * SYS; i += 512) { sy0[i] = (f16)0.f; sy1[i] = (f16)0.f; }
    for (int i = tid; i < MR * SXS; i += 512) { sh16[i] = (f16)0.f; }
    for (int i = tid; i < MR * SZS; i += 512) { shf[i] = 0.f; }

    f16x8 wrh[4], wzh[4], w0h[4], wrx[4], wzx[4], w0x[4];
    #pragma unroll
    for (int kt = 0; kt < 4; ++kt) {
        f16x8 a, b, c, d, e, f;
        #pragma unroll
        for (int j = 0; j < 8; ++j) {
            const int k = kt * 32 + kg * 8 + j;
            a[j] = (f16)r_w [(size_t)(DI + k) * DH + col];
            b[j] = (f16)z_w [(size_t)(DI + k) * DH + col];
            c[j] = (f16)h_w0[(size_t)(DI + k) * DM + col];
            d[j] = (f16)r_w [(size_t)k * DH + col];
            e[j] = (f16)z_w [(size_t)k * DH + col];
            f[j] = (f16)h_w0[(size_t)k * DM + col];
        }
        wrh[kt] = a; wzh[kt] = b; w0h[kt] = c; wrx[kt] = d; wzx[kt] = e; w0x[kt] = f;
    }
    f16x8 w1f[5], w2f[5];
    #pragma unroll
    for (int kt = 0; kt < 5; ++kt) {
        f16x8 a, b;
        #pragma unroll
        for (int j = 0; j < 8; ++j) {
            const int k = kt * 32 + kg * 8 + j;
            const bool in = (k < DM);
            a[j] = in ? (f16)h_w1[(size_t)k * DM + col] : (f16)0.f;
            b[j] = in ? (f16)h_w2[(size_t)k * DH + col] : (f16)0.f;
        }
        w1f[kt] = a; w2f[kt] = b;
    }
    f16x8 ext[5];
    #pragma unroll
    for (int kt = 0; kt < 5; ++kt) {
        f16x8 f;
        #pragma unroll
        for (int j = 0; j < 8; ++j) {
            const int k = kt * 32 + kg * 8 + j;
            float v = 0.f;
            if (w == 0 && kt < 4)      v = (float)h_w0[(size_t)(DI + k) * DM + 128 + ln];
            else if (w == 1 && k < DM) v = (float)h_w1[(size_t)k * DM + 128 + ln];
            else if (w == 2 && kt < 4) v = (float)h_w0[(size_t)k * DM + 128 + ln];
            f[j] = (f16)v;
        }
        ext[kt] = f;
    }

    const float b1r = r_b[col], b1z = z_b[col];
    const float b2  = h_b0[col], b3 = h_b1[col], b4 = h_b2[col];
    const float bext = (w == 0) ? h_b0[128 + ln] : (w == 1) ? h_b1[128 + ln] : 0.f;

    float* op[4];
    #pragma unroll
    for (int j = 0; j < 4; ++j)
        op[j] = out + (size_t)(b0 + 4 * kg + j) * SEQ * DH + col;

    const bool xldr = (tid < 256);
    const int  xrow = tid >> 4;
    const int  xseg = tid & 15;
    const float* __restrict__ xbase = inputs + (size_t)(b0 + (xrow & 15)) * SEQ * DI + xseg * 8;

    float4 xpA0 = {0,0,0,0}, xpA1 = {0,0,0,0};
    if (xldr) {
        const float4 a = ((const float4*)xbase)[0];
        const float4 b = ((const float4*)(xbase + 4))[0];
        f16x8 v; v[0]=(f16)a.x; v[1]=(f16)a.y; v[2]=(f16)a.z; v[3]=(f16)a.w;
                 v[4]=(f16)b.x; v[5]=(f16)b.y; v[6]=(f16)b.z; v[7]=(f16)b.w;
        *(f16x8*)(sx + xrow * SXS + xseg * 8) = v;
        xpA0 = ((const float4*)(xbase + (size_t)1 * DI))[0];
        xpA1 = ((const float4*)(xbase + (size_t)1 * DI + 4))[0];
    }
    bar_lds();
    {
        f16x8 xa[4];
        #pragma unroll
        for (int kt = 0; kt < 4; ++kt)
            xa[kt] = *(const f16x8*)(sx + ln * SXS + kt * 32 + kg * 8);
        f32x4 a = {0,0,0,0};
        #pragma unroll
        for (int kt = 0; kt < 4; ++kt) a = MFMA16(xa[kt], wrx[kt], a);
        *(f32x4*)(pg + (unsigned)col * PGS + kg * 4) = a;
        f32x4 b = {0,0,0,0};
        #pragma unroll
        for (int kt = 0; kt < 4; ++kt) b = MFMA16(xa[kt], wzx[kt], b);
        *(f32x4*)(pg + (unsigned)(128 + col) * PGS + kg * 4) = b;
        f32x4 c = {0,0,0,0};
        #pragma unroll
        for (int kt = 0; kt < 4; ++kt) c = MFMA16(xa[kt], w0x[kt], c);
        *(f32x4*)(pm + (unsigned)col * PGS + kg * 4) = c;
        if (w == 2) {
            f32x4 d = {0,0,0,0};
            #pragma unroll
            for (int kt = 0; kt < 4; ++kt) d = MFMA16(xa[kt], ext[kt], d);
            *(f32x4*)(pm + (unsigned)(128 + ln) * PGS + kg * 4) = d;
        }
    }
    bar_lds();

    for (int t = 0; t < SEQ; ++t) {
        float4 xpB0, xpB1;
        if (xldr) {
            const int tn = (t + 2 < SEQ) ? t + 2 : SEQ - 1;
            xpB0 = ((const float4*)(xbase + (size_t)tn * DI))[0];
            xpB1 = ((const float4*)(xbase + (size_t)tn * DI + 4))[0];
        }
        f16x8 ha[4];
        #pragma unroll
        for (int kt = 0; kt < 4; ++kt)
            ha[kt] = *(const f16x8*)(sh16 + ln * SXS + kt * 32 + kg * 8);
        f32x4 ar = *(const f32x4*)(pg + (unsigned)col * PGS + kg * 4);
        #pragma unroll
        for (int kt = 0; kt < 4; ++kt) ar = MFMA16(ha[kt], wrh[kt], ar);
        #pragma unroll
        for (int j = 0; j < 4; ++j) {
            const int m = 4 * kg + j;
            const float g = sigm(ar[j] + b1r);
            srh[m * SXS + col] = (f16)(g * shf[m * SZS + col]);
        }
        bar_lds();

        f32x4 pzv = *(const f32x4*)(pg + (unsigned)(128 + col) * PGS + kg * 4);
        #pragma unroll
        for (int kt = 0; kt < 4; ++kt) pzv = MFMA16(ha[kt], wzh[kt], pzv);
        f16x8 ra[4];
        #pragma unroll
        for (int kt = 0; kt < 4; ++kt)
            ra[kt] = *(const f16x8*)(srh + ln * SXS + kt * 32 + kg * 8);
        f32x4 a0 = *(const f32x4*)(pm + (unsigned)col * PGS + kg * 4);
        #pragma unroll
        for (int kt = 0; kt < 4; ++kt) a0 = MFMA16(ra[kt], w0h[kt], a0);
        #pragma unroll
        for (int j = 0; j < 4; ++j)
            sy0[(4 * kg + j) * SYS + col] = (f16)fmaxf(a0[j] + b2, 0.f);
        if (w == 0) {
            f32x4 a8 = *(const f32x4*)(pm + (unsigned)(128 + ln) * PGS + kg * 4);
            #pragma unroll
            for (int kt = 0; kt < 4; ++kt) a8 = MFMA16(ra[kt], ext[kt], a8);
            #pragma unroll
            for (int j = 0; j < 4; ++j)
                sy0[(4 * kg + j) * SYS + 128 + ln] = (f16)fmaxf(a8[j] + bext, 0.f);
        }
        if (xldr) {
            f16x8 v; v[0]=(f16)xpA0.x; v[1]=(f16)xpA0.y; v[2]=(f16)xpA0.z; v[3]=(f16)xpA0.w;
                     v[4]=(f16)xpA1.x; v[5]=(f16)xpA1.y; v[6]=(f16)xpA1.z; v[7]=(f16)xpA1.w;
            *(f16x8*)(sx + xrow * SXS + xseg * 8) = v;
        }
        bar_lds();

        f16x8 ya[5];
        #pragma unroll
        for (int kt = 0; kt < 5; ++kt)
            ya[kt] = *(const f16x8*)(sy0 + ln * SYS + kt * 32 + kg * 8);
        f32x4 a1 = {0,0,0,0};
        #pragma unroll
        for (int kt = 0; kt < 5; ++kt) a1 = MFMA16(ya[kt], w1f[kt], a1);
        #pragma unroll
        for (int j = 0; j < 4; ++j)
            sy1[(4 * kg + j) * SYS + col] = (f16)fmaxf(a1[j] + b3, 0.f);
        if (w == 1) {
            f32x4 a8 = {0,0,0,0};
            #pragma unroll
            for (int kt = 0; kt < 5; ++kt) a8 = MFMA16(ya[kt], ext[kt], a8);
            #pragma unroll
            for (int j = 0; j < 4; ++j)
                sy1[(4 * kg + j) * SYS + 128 + ln] = (f16)fmaxf(a8[j] + bext, 0.f);
        }
        #pragma unroll
        for (int j = 0; j < 4; ++j)
            sz[(4 * kg + j) * SZS + col] = sigm(pzv[j] + b1z);
        f16x8 xa[4];
        #pragma unroll
        for (int kt = 0; kt < 4; ++kt)
            xa[kt] = *(const f16x8*)(sx + ln * SXS + kt * 32 + kg * 8);
        {
            f32x4 a = {0,0,0,0};
            #pragma unroll
            for (int kt = 0; kt < 4; ++kt) a = MFMA16(xa[kt], wrx[kt], a);
            *(f32x4*)(pg + (unsigned)col * PGS + kg * 4) = a;
            f32x4 b = {0,0,0,0};
            #pragma unroll
            for (int kt = 0; kt < 4; ++kt) b = MFMA16(xa[kt], wzx[kt], b);
            *(f32x4*)(pg + (unsigned)(128 + col) * PGS + kg * 4) = b;
        }
        bar_lds();

        f16x8 za[5];
        #pragma unroll
        for (int kt = 0; kt < 5; ++kt)
            za[kt] = *(const f16x8*)(sy1 + ln * SYS + kt * 32 + kg * 8);
        f32x4 a2 = {0,0,0,0};
        #pragma unroll
        for (int kt = 0; kt < 5; ++kt) a2 = MFMA16(za[kt], w2f[kt], a2);
        {
            f32x4 a = {0,0,0,0};
            #pragma unroll
            for (int kt = 0; kt < 4; ++kt) a = MFMA16(xa[kt], w0x[kt], a);
            *(f32x4*)(pm + (unsigned)col * PGS + kg * 4) = a;
            if (w == 2) {
                f32x4 d = {0,0,0,0};
                #pragma unroll
                for (int kt = 0; kt < 4; ++kt) d = MFMA16(xa[kt], ext[kt], d);
                *(f32x4*)(pm + (unsigned)(128 + ln) * PGS + kg * 4) = d;
            }
        }
        #pragma unroll
        for (int j = 0; j < 4; ++j) {
            const int m = 4 * kg + j;
            const float ht = tanh_fast(a2[j] + b4);
            const float zz = sz[m * SZS + col];
            const float hn = (1.f - zz) * shf[m * SZS + col] + zz * ht;
            shf[m * SZS + col] = hn;
            sh16[m * SXS + col] = (f16)hn;
            *op[j] = hn; op[j] += DH;
        }
        bar_lds();
        xpA0 = xpB0; xpA1 = xpB1;
    }

    for (int i = tid; i < MR * DH; i += 512)
        hid_out[(size_t)(b0 + (i >> 7)) * DH + (i & 127)] = shf[(i >> 7) * SZS + (i & 127)];
}

extern "C" void kernel_launch(void* const* d_in, const int* in_sizes, int n_in,
                              void* d_out, int out_size, void* d_ws, size_t ws_size,
                              hipStream_t stream) {
    const float* inputs = (const float*)d_in[0];
    const float* r_w  = (const float*)d_in[1];
    const float* r_b  = (const float*)d_in[2];
    const float* z_w  = (const float*)d_in[3];
    const float* z_b  = (const float*)d_in[4];
    const float* h_w0 = (const float*)d_in[5];
    const float* h_b0 = (const float*)d_in[6];
    const float* h_w1 = (const float*)d_in[7];
    const float* h_b1 = (const float*)d_in[8];
    const float* h_w2 = (const float*)d_in[9];
    const float* h_b2 = (const float*)d_in[10];

    float* out = (float*)d_out;
    float* hid = out + (size_t)BATCH * SEQ * DH;

    if (ws_size >= WS_ELEMS * sizeof(f16)) {
        f16* ws = (f16*)d_ws;
        hipLaunchKernelGGL(xproj_kernel, dim3(16 * 32), dim3(512), 0, stream,
                           inputs, r_w, z_w, h_w0, ws);
        hipLaunchKernelGGL(hgru_kernel, dim3(BATCH / MR), dim3(512), 0, stream,
                           ws, r_w, r_b, z_w, z_b,
                           h_w0, h_b0, h_w1, h_b1, h_w2, h_b2,
                           out, hid);
    } else {
        hipLaunchKernelGGL(hgru_fallback, dim3(BATCH / MR), dim3(512), 0, stream,
                           inputs, r_w, r_b, z_w, z_b,
                           h_w0, h_b0, h_w1, h_b1, h_w2, h_b2,
                           out, hid);
    }
}

// Round 16
// 1791.388 us; speedup vs baseline: 1.0450x; 1.0450x over previous
//
#include <hip/hip_runtime.h>
#include <math.h>

typedef _Float16 f16;
typedef _Float16 f16x8 __attribute__((ext_vector_type(8)));
typedef _Float16 f16x4 __attribute__((ext_vector_type(4)));
typedef float    f32x4 __attribute__((ext_vector_type(4)));

#define BATCH 256
#define SEQ   1024
#define DI    128
#define DH    128
#define DM    144
#define MR    16
#define SXS   132   // f16 panel stride (4*66 dw = 8 mod 32)
#define SYS   164   // f16 stride, 160-col panels
#define SZS   134   // f32 stride (fallback only)
#define PGS   20    // (fallback only)
#define NW    400   // xproj cols: r 0-127, z 128-255, mlp0 256-399
#define WS_ELEMS ((size_t)16 * SEQ * NW * 16)

#define MFMA16(a, b, c) __builtin_amdgcn_mfma_f32_16x16x32_f16((a), (b), (c), 0, 0, 0)

// rcp-based activations: v_rcp_f32 instead of IEEE divide (saves Newton iters;
// ~1e-6 rel error, far inside the 1.86e-2 absmax budget)
__device__ __forceinline__ float sigm(float x) {
    return __builtin_amdgcn_rcpf(1.f + __expf(-x));
}
__device__ __forceinline__ float tanh_fast(float x) {
    const float e = __expf(2.f * x);
    return 1.f - 2.f * __builtin_amdgcn_rcpf(e + 1.f);
}
// LDS-only barrier: global loads/stores stay in flight (T4).
__device__ __forceinline__ void bar_lds() {
    asm volatile("s_waitcnt lgkmcnt(0)" ::: "memory");
    __builtin_amdgcn_s_barrier();
}
__device__ __forceinline__ f32x4 cvt4(f16x4 v) {
    f32x4 r; r[0] = (float)v[0]; r[1] = (float)v[1]; r[2] = (float)v[2]; r[3] = (float)v[3];
    return r;
}

// ===================== pre-pass: xproj = x @ [r_w | z_w | h_w0(x-rows)] =====================
__global__ __launch_bounds__(512, 2) void xproj_kernel(
    const float* __restrict__ inputs,
    const float* __restrict__ r_w, const float* __restrict__ z_w,
    const float* __restrict__ h_w0, f16* __restrict__ ws)
{
    __shared__ __align__(16) f16 lx[16 * SXS];

    const int rb = blockIdx.x >> 5;
    const int tc = blockIdx.x & 31;
    const int tid = threadIdx.x;
    const int w   = tid >> 6;
    const int ln  = tid & 15;
    const int kg  = (tid & 63) >> 4;
    const int b0  = rb * MR;

    const int nt = (w == 0) ? 4 : 3;
    f16x8 wb[4][4];
    #pragma unroll
    for (int i = 0; i < 4; ++i) if (i < nt) {
        const int tile = w + 8 * i;
        #pragma unroll
        for (int kt = 0; kt < 4; ++kt) {
            f16x8 f;
            #pragma unroll
            for (int j = 0; j < 8; ++j) {
                const int k = kt * 32 + kg * 8 + j;
                float v;
                if (tile < 8)       v = r_w [(size_t)k * DH + tile * 16 + ln];
                else if (tile < 16) v = z_w [(size_t)k * DH + (tile - 8) * 16 + ln];
                else                v = h_w0[(size_t)k * DM + (tile - 16) * 16 + ln];
                f[j] = (f16)v;
            }
            wb[i][kt] = f;
        }
    }

    for (int tt = 0; tt < 32; ++tt) {
        const int t = tc * 32 + tt;
        if (tid < 256) {
            const int row = tid >> 4, seg = tid & 15;
            const float* xb = inputs + ((size_t)(b0 + row) * SEQ + t) * DI + seg * 8;
            const float4 a = ((const float4*)xb)[0];
            const float4 b = ((const float4*)(xb + 4))[0];
            f16x8 v; v[0]=(f16)a.x; v[1]=(f16)a.y; v[2]=(f16)a.z; v[3]=(f16)a.w;
                     v[4]=(f16)b.x; v[5]=(f16)b.y; v[6]=(f16)b.z; v[7]=(f16)b.w;
            *(f16x8*)(lx + row * SXS + seg * 8) = v;
        }
        __syncthreads();
        f16x8 xa[4];
        #pragma unroll
        for (int kt = 0; kt < 4; ++kt)
            xa[kt] = *(const f16x8*)(lx + ln * SXS + kt * 32 + kg * 8);
        #pragma unroll
        for (int i = 0; i < 4; ++i) if (i < nt) {
            const int tile = w + 8 * i;
            f32x4 a = {0.f, 0.f, 0.f, 0.f};
            #pragma unroll
            for (int kt = 0; kt < 4; ++kt) a = MFMA16(xa[kt], wb[i][kt], a);
            f16x4 o; o[0]=(f16)a[0]; o[1]=(f16)a[1]; o[2]=(f16)a[2]; o[3]=(f16)a[3];
            *(f16x4*)(ws + ((size_t)(rb * SEQ + t) * NW + tile * 16 + ln) * 16 + kg * 4) = o;
        }
        __syncthreads();
    }
}

// ===================== main RNN kernel (R14 champion, restored) =====================
__global__ __launch_bounds__(512, 2) __attribute__((amdgpu_waves_per_eu(2, 2)))
void hgru_kernel(
    const f16* __restrict__ ws,
    const float* __restrict__ r_w, const float* __restrict__ r_b,
    const float* __restrict__ z_w, const float* __restrict__ z_b,
    const float* __restrict__ h_w0, const float* __restrict__ h_b0,
    const float* __restrict__ h_w1, const float* __restrict__ h_b1,
    const float* __restrict__ h_w2, const float* __restrict__ h_b2,
    float* __restrict__ out, float* __restrict__ hid_out)
{
    __shared__ __align__(16) f16 sh16[MR * SXS];  // h f16 A-panel
    __shared__ __align__(16) f16 srh[MR * SXS];   // r*h A-panel
    __shared__ __align__(16) f16 sy0[MR * SYS];   // mlp act1 (padded to 160)
    __shared__ __align__(16) f16 sy1[MR * SYS];   // mlp act2

    const int tid  = threadIdx.x;
    const int w    = tid >> 6;      // wave 0..7
    const int lane = tid & 63;
    const int ln   = lane & 15;
    const int kg   = lane >> 4;     // C rows 4*kg..4*kg+3
    const int rb   = blockIdx.x;
    const int b0   = rb * MR;
    const int col  = w * 16 + ln;

    for (int i = tid; i < MR * SYS; i += 512) { sy0[i] = (f16)0.f; sy1[i] = (f16)0.f; }
    for (int i = tid; i < MR * SXS; i += 512) { sh16[i] = (f16)0.f; }

    // ---- register weight fragments (h-rows + MLP interior) ----
    f16x8 wrh[4], wzh[4], w0h[4];
    #pragma unroll
    for (int kt = 0; kt < 4; ++kt) {
        f16x8 a, b, c;
        #pragma unroll
        for (int j = 0; j < 8; ++j) {
            const int k = DI + kt * 32 + kg * 8 + j;
            a[j] = (f16)r_w [(size_t)k * DH + col];
            b[j] = (f16)z_w [(size_t)k * DH + col];
            c[j] = (f16)h_w0[(size_t)k * DM + col];
        }
        wrh[kt] = a; wzh[kt] = b; w0h[kt] = c;
    }
    f16x8 w1f[5], w2f[5];
    #pragma unroll
    for (int kt = 0; kt < 5; ++kt) {
        f16x8 a, b;
        #pragma unroll
        for (int j = 0; j < 8; ++j) {
            const int k = kt * 32 + kg * 8 + j;
            const bool in = (k < DM);
            a[j] = in ? (f16)h_w1[(size_t)k * DM + col] : (f16)0.f;
            b[j] = in ? (f16)h_w2[(size_t)k * DH + col] : (f16)0.f;
        }
        w1f[kt] = a; w2f[kt] = b;
    }
    // ext: w==0 -> y0 tile8 (h-rows of h_w0); w==1 -> y1 tile8 (h_w1)
    f16x8 ext[5];
    #pragma unroll
    for (int kt = 0; kt < 5; ++kt) {
        f16x8 f;
        #pragma unroll
        for (int j = 0; j < 8; ++j) {
            const int k = kt * 32 + kg * 8 + j;
            float v = 0.f;
            if (w == 0 && kt < 4)      v = (float)h_w0[(size_t)(DI + k) * DM + 128 + ln];
            else if (w == 1 && k < DM) v = (float)h_w1[(size_t)k * DM + 128 + ln];
            f[j] = (f16)v;
        }
        ext[kt] = f;
    }

    const float b1r = r_b[col], b1z = z_b[col];
    const float b2  = h_b0[col], b3 = h_b1[col], b4 = h_b2[col];
    const float bext = (w == 0) ? h_b0[128 + ln] : (w == 1) ? h_b1[128 + ln] : 0.f;

    float* op[4];
    #pragma unroll
    for (int j = 0; j < 4; ++j)
        op[j] = out + (size_t)(b0 + 4 * kg + j) * SEQ * DH + col;

    // ---- ws C-in streams ----
    const size_t stepAdv = (size_t)NW * 16;
    const f16* pr = ws + ((size_t)rb * SEQ) * stepAdv + ((size_t)(      col) * 16 + kg * 4);
    const f16* pz = ws + ((size_t)rb * SEQ) * stepAdv + ((size_t)(128 + col) * 16 + kg * 4);
    const f16* pm = ws + ((size_t)rb * SEQ) * stepAdv + ((size_t)(256 + col) * 16 + kg * 4);
    const f16* p8 = ws + ((size_t)rb * SEQ) * stepAdv + ((size_t)(384 + ln ) * 16 + kg * 4);

    f16x4 curR = *(const f16x4*)pr;
    f16x4 curZ = *(const f16x4*)pz;
    f16x4 curM = *(const f16x4*)pm;
    f16x4 cur8 = (w == 0) ? *(const f16x4*)p8 : f16x4{0, 0, 0, 0};

    // per-wave register state: h rows 4kg+j at this wave's col; z gate likewise
    f32x4 hreg = {0.f, 0.f, 0.f, 0.f};
    f32x4 zreg = {0.f, 0.f, 0.f, 0.f};

    bar_lds();

    const f32x4 z4 = {0.f, 0.f, 0.f, 0.f};

    for (int t = 0; t < SEQ; ++t) {
        // ======== s1: issue critical ha ds_reads FIRST ========
        f16x8 ha[4];
        #pragma unroll
        for (int kt = 0; kt < 4; ++kt)
            ha[kt] = *(const f16x8*)(sh16 + ln * SXS + kt * 32 + kg * 8);

        // prefetch next step's C-ins (issued after ha reads; full step of cover)
        const size_t nadv = (size_t)((t + 1 < SEQ) ? t + 1 : t) * stepAdv;
        const f16x4 nxtR = *(const f16x4*)(pr + nadv);
        const f16x4 nxtZ = *(const f16x4*)(pz + nadv);
        const f16x4 nxtM = *(const f16x4*)(pm + nadv);
        const f16x4 nxt8 = (w == 0) ? *(const f16x4*)(p8 + nadv) : f16x4{0, 0, 0, 0};

        // r gate (split 2+2 chains); h from registers
        f32x4 r0 = cvt4(curR), r1 = z4;
        r0 = MFMA16(ha[0], wrh[0], r0);
        r1 = MFMA16(ha[1], wrh[1], r1);
        r0 = MFMA16(ha[2], wrh[2], r0);
        r1 = MFMA16(ha[3], wrh[3], r1);
        const f32x4 ar = r0 + r1;
        #pragma unroll
        for (int j = 0; j < 4; ++j) {
            const float g = sigm(ar[j] + b1r);
            srh[(4 * kg + j) * SXS + col] = (f16)(g * hreg[j]);
        }
        bar_lds(); // A

        // ======== s2: y0 (split chains) + z h-part shadow (reuses ha) ========
        f32x4 zc0 = cvt4(curZ), zc1 = z4;
        zc0 = MFMA16(ha[0], wzh[0], zc0);
        zc1 = MFMA16(ha[1], wzh[1], zc1);
        zc0 = MFMA16(ha[2], wzh[2], zc0);
        zc1 = MFMA16(ha[3], wzh[3], zc1);

        f16x8 ra[4];
        #pragma unroll
        for (int kt = 0; kt < 4; ++kt)
            ra[kt] = *(const f16x8*)(srh + ln * SXS + kt * 32 + kg * 8);
        f32x4 m0 = cvt4(curM), m1 = z4;
        m0 = MFMA16(ra[0], w0h[0], m0);
        m1 = MFMA16(ra[1], w0h[1], m1);
        m0 = MFMA16(ra[2], w0h[2], m0);
        m1 = MFMA16(ra[3], w0h[3], m1);
        const f32x4 a0 = m0 + m1;
        #pragma unroll
        for (int j = 0; j < 4; ++j)
            sy0[(4 * kg + j) * SYS + col] = (f16)fmaxf(a0[j] + b2, 0.f);
        if (w == 0) {
            f32x4 e0 = cvt4(cur8), e1 = z4;
            e0 = MFMA16(ra[0], ext[0], e0);
            e1 = MFMA16(ra[1], ext[1], e1);
            e0 = MFMA16(ra[2], ext[2], e0);
            e1 = MFMA16(ra[3], ext[3], e1);
            const f32x4 a8 = e0 + e1;
            #pragma unroll
            for (int j = 0; j < 4; ++j)
                sy0[(4 * kg + j) * SYS + 128 + ln] = (f16)fmaxf(a8[j] + bext, 0.f);
        }
        // z epilogue -> registers (consumed by s4, same wave/lane)
        {
            const f32x4 zc = zc0 + zc1;
            #pragma unroll
            for (int j = 0; j < 4; ++j) zreg[j] = sigm(zc[j] + b1z);
        }
        bar_lds(); // B

        // ======== s3: y1 (split 3+2 chains) ========
        f16x8 ya[5];
        #pragma unroll
        for (int kt = 0; kt < 5; ++kt)
            ya[kt] = *(const f16x8*)(sy0 + ln * SYS + kt * 32 + kg * 8);
        f32x4 c0 = z4, c1 = z4;
        c0 = MFMA16(ya[0], w1f[0], c0);
        c1 = MFMA16(ya[1], w1f[1], c1);
        c0 = MFMA16(ya[2], w1f[2], c0);
        c1 = MFMA16(ya[3], w1f[3], c1);
        c0 = MFMA16(ya[4], w1f[4], c0);
        const f32x4 a1 = c0 + c1;
        #pragma unroll
        for (int j = 0; j < 4; ++j)
            sy1[(4 * kg + j) * SYS + col] = (f16)fmaxf(a1[j] + b3, 0.f);
        if (w == 1) {
            f32x4 e0 = z4, e1 = z4;
            e0 = MFMA16(ya[0], ext[0], e0);
            e1 = MFMA16(ya[1], ext[1], e1);
            e0 = MFMA16(ya[2], ext[2], e0);
            e1 = MFMA16(ya[3], ext[3], e1);
            e0 = MFMA16(ya[4], ext[4], e0);
            const f32x4 a8 = e0 + e1;
            #pragma unroll
            for (int j = 0; j < 4; ++j)
                sy1[(4 * kg + j) * SYS + 128 + ln] = (f16)fmaxf(a8[j] + bext, 0.f);
        }
        bar_lds(); // C

        // ======== s4: h~ (split 3+2); h update in registers ========
        f16x8 za[5];
        #pragma unroll
        for (int kt = 0; kt < 5; ++kt)
            za[kt] = *(const f16x8*)(sy1 + ln * SYS + kt * 32 + kg * 8);
        f32x4 d0 = z4, d1 = z4;
        d0 = MFMA16(za[0], w2f[0], d0);
        d1 = MFMA16(za[1], w2f[1], d1);
        d0 = MFMA16(za[2], w2f[2], d0);
        d1 = MFMA16(za[3], w2f[3], d1);
        d0 = MFMA16(za[4], w2f[4], d0);
        const f32x4 hv = d0 + d1;
        #pragma unroll
        for (int j = 0; j < 4; ++j) {
            const float ht = tanh_fast(hv[j] + b4);
            const float hn = (1.f - zreg[j]) * hreg[j] + zreg[j] * ht;
            hreg[j] = hn;
            sh16[(4 * kg + j) * SXS + col] = (f16)hn;
            *op[j] = hn; op[j] += DH;   // fire-and-forget, stays in VMEM queue
        }
        bar_lds(); // D

        curR = nxtR; curZ = nxtZ; curM = nxtM; cur8 = nxt8;
    }

    // final hidden state from registers (each lane owns rows 4kg+j at col)
    #pragma unroll
    for (int j = 0; j < 4; ++j)
        hid_out[(size_t)(b0 + 4 * kg + j) * DH + col] = hreg[j];
}

// ===================== fallback (R8 monolithic) if ws too small =====================
__global__ __launch_bounds__(512, 2) __attribute__((amdgpu_waves_per_eu(2, 2)))
void hgru_fallback(
    const float* __restrict__ inputs,
    const float* __restrict__ r_w, const float* __restrict__ r_b,
    const float* __restrict__ z_w, const float* __restrict__ z_b,
    const float* __restrict__ h_w0, const float* __restrict__ h_b0,
    const float* __restrict__ h_w1, const float* __restrict__ h_b1,
    const float* __restrict__ h_w2, const float* __restrict__ h_b2,
    float* __restrict__ out, float* __restrict__ hid_out)
{
    __shared__ __align__(16) f16   sx [MR * SXS];
    __shared__ __align__(16) f16   sh16[MR * SXS];
    __shared__ __align__(16) f16   srh[MR * SXS];
    __shared__ __align__(16) f16   sy0[MR * SYS];
    __shared__ __align__(16) f16   sy1[MR * SYS];
    __shared__ __align__(16) float sz [MR * SZS];
    __shared__ __align__(16) float shf[MR * SZS];
    __shared__ __align__(16) float pg[256 * PGS];
    __shared__ __align__(16) float pm[DM  * PGS];

    const int tid  = threadIdx.x;
    const int w    = tid >> 6;
    const int lane = tid & 63;
    const int ln   = lane & 15;
    const int kg   = lane >> 4;
    const int b0   = blockIdx.x * MR;
    const int col  = w * 16 + ln;

    for (int i = tid; i < MR * SYS; i += 512) { sy0[i] = (f16)0.f; sy1[i] = (f16)0.f; }
    for (int i = tid; i < MR * SXS; i += 512) { sh16[i] = (f16)0.f; }
    for (int i = tid; i < MR * SZS; i += 512) { shf[i] = 0.f; }

    f16x8 wrh[4], wzh[4], w0h[4], wrx[4], wzx[4], w0x[4];
    #pragma unroll
    for (int kt = 0; kt < 4; ++kt) {
        f16x8 a, b, c, d, e, f;
        #pragma unroll
        for (int j = 0; j < 8; ++j) {
            const int k = kt * 32 + kg * 8 + j;
            a[j] = (f16)r_w [(size_t)(DI + k) * DH + col];
            b[j] = (f16)z_w [(size_t)(DI + k) * DH + col];
            c[j] = (f16)h_w0[(size_t)(DI + k) * DM + col];
            d[j] = (f16)r_w [(size_t)k * DH + col];
            e[j] = (f16)z_w [(size_t)k * DH + col];
            f[j] = (f16)h_w0[(size_t)k * DM + col];
        }
        wrh[kt] = a; wzh[kt] = b; w0h[kt] = c; wrx[kt] = d; wzx[kt] = e; w0x[kt] = f;
    }
    f16x8 w1f[5], w2f[5];
    #pragma unroll
    for (int kt = 0; kt < 5; ++kt) {
        f16x8 a, b;
        #pragma unroll
        for (int j = 0; j < 8; ++j) {
            const int k = kt * 32 + kg * 8 + j;
            const bool in = (k < DM);
            a[j] = in ? (f16)h_w1[(size_t)k * DM + col] : (f16)0.f;
            b[j] = in ? (f16)h_w2[(size_t)k * DH + col] : (f16)0.f;
        }
        w1f[kt] = a; w2f[kt] = b;
    }
    f16x8 ext[5];
    #pragma unroll
    for (int kt = 0; kt < 5; ++kt) {
        f16x8 f;
        #pragma unroll
        for (int j = 0; j < 8; ++j) {
            const int k = kt * 32 + kg * 8 + j;
            float v = 0.f;
            if (w == 0 && kt < 4)      v = (float)h_w0[(size_t)(DI + k) * DM + 128 + ln];
            else if (w == 1 && k < DM) v = (float)h_w1[(size_t)k * DM + 128 + ln];
            else if (w == 2 && kt < 4) v = (float)h_w0[(size_t)k * DM + 128 + ln];
            f[j] = (f16)v;
        }
        ext[kt] = f;
    }

    const float b1r = r_b[col], b1z = z_b[col];
    const float b2  = h_b0[col], b3 = h_b1[col], b4 = h_b2[col];
    const float bext = (w == 0) ? h_b0[128 + ln] : (w == 1) ? h_b1[128 + ln] : 0.f;

    float* op[4];
    #pragma unroll
    for (int j = 0; j < 4; ++j)
        op[j] = out + (size_t)(b0 + 4 * kg + j) * SEQ * DH + col;

    const bool xldr = (tid < 256);
    const int  xrow = tid >> 4;
    const int  xseg = tid & 15;
    const float* __restrict__ xbase = inputs + (size_t)(b0 + (xrow & 15)) * SEQ * DI + xseg * 8;

    float4 xpA0 = {0,0,0,0}, xpA1 = {0,0,0,0};
    if (xldr) {
        const float4 a = ((const float4*)xbase)[0];
        const float4 b = ((const float4*)(xbase + 4))[0];
        f16x8 v; v[0]=(f16)a.x; v[1]=(f16)a.y; v[2]=(f16)a.z; v[3]=(f16)a.w;
                 v[4]=(f16)b.x; v[5]=(f16)b.y; v[6]=(f16)b.z; v[7]=(f16)b.w;
        *(f16x8*)(sx + xrow * SXS + xseg * 8) = v;
        xpA0 = ((const float4*)(xbase + (size_t)1 * DI))[0];
        xpA1 = ((const float4*)(xbase + (size_t)1 * DI + 4))[0];
    }
    bar_lds();
    {
        f16x8 xa[4];
        #pragma unroll
        for (int kt = 0; kt < 4; ++kt)
            xa[kt] = *(const f16x8*)(sx + ln * SXS + kt * 32 + kg * 8);
        f32x4 a = {0,0,0,0};
        #pragma unroll
        for (int kt = 0; kt < 4; ++kt) a = MFMA16(xa[kt], wrx[kt], a);
        *(f32x4*)(pg + (unsigned)col * PGS + kg * 4) = a;
        f32x4 b = {0,0,0,0};
        #pragma unroll
        for (int kt = 0; kt < 4; ++kt) b = MFMA16(xa[kt], wzx[kt], b);
        *(f32x4*)(pg + (unsigned)(128 + col) * PGS + kg * 4) = b;
        f32x4 c = {0,0,0,0};
        #pragma unroll
        for (int kt = 0; kt < 4; ++kt) c = MFMA16(xa[kt], w0x[kt], c);
        *(f32x4*)(pm + (unsigned)col * PGS + kg * 4) = c;
        if (w == 2) {
            f32x4 d = {0,0,0,0};
            #pragma unroll
            for (int kt = 0; kt < 4; ++kt) d = MFMA16(xa[kt], ext[kt], d);
            *(f32x4*)(pm + (unsigned)(128 + ln) * PGS + kg * 4) = d;
        }
    }
    bar_lds();

    for (int t = 0; t < SEQ; ++t) {
        float4 xpB0, xpB1;
        if (xldr) {
            const int tn = (t + 2 < SEQ) ? t + 2 : SEQ - 1;
            xpB0 = ((const float4*)(xbase + (size_t)tn * DI))[0];
            xpB1 = ((const float4*)(xbase + (size_t)tn * DI + 4))[0];
        }
        f16x8 ha[4];
        #pragma unroll
        for (int kt = 0; kt < 4; ++kt)
            ha[kt] = *(const f16x8*)(sh16 + ln * SXS + kt * 32 + kg * 8);
        f32x4 ar = *(const f32x4*)(pg + (unsigned)col * PGS + kg * 4);
        #pragma unroll
        for (int kt = 0; kt < 4; ++kt) ar = MFMA16(ha[kt], wrh[kt], ar);
        #pragma unroll
        for (int j = 0; j < 4; ++j) {
            const int m = 4 * kg + j;
            const float g = sigm(ar[j] + b1r);
            srh[m * SXS + col] = (f16)(g * shf[m * SZS + col]);
        }
        bar_lds();

        f32x4 pzv = *(const f32x4*)(pg + (unsigned)(128 + col) * PGS + kg * 4);
        #pragma unroll
        for (int kt = 0; kt < 4; ++kt) pzv = MFMA16(ha[kt], wzh[kt], pzv);
        f16x8 ra[4];
        #pragma unroll
        for (int kt = 0; kt < 4; ++kt)
            ra[kt] = *(const f16x8*)(srh + ln * SXS + kt * 32 + kg * 8);
        f32x4 a0 = *(const f32x4*)(pm + (unsigned)col * PGS + kg * 4);
        #pragma unroll
        for (int kt = 0; kt < 4; ++kt) a0 = MFMA16(ra[kt], w0h[kt], a0);
        #pragma unroll
        for (int j = 0; j < 4; ++j)
            sy0[(4 * kg + j) * SYS + col] = (f16)fmaxf(a0[j] + b2, 0.f);
        if (w == 0) {
            f32x4 a8 = *(const f32x4*)(pm + (unsigned)(128 + ln) * PGS + kg * 4);
            #pragma unroll
            for (int kt = 0; kt < 4; ++kt) a8 = MFMA16(ra[kt], ext[kt], a8);
            #pragma unroll
            for (int j = 0; j < 4; ++j)
                sy0[(4 * kg + j) * SYS + 128 + ln] = (f16)fmaxf(a8[j] + bext, 0.f);
        }
        if (xldr) {
            f16x8 v; v[0]=(f16)xpA0.x; v[1]=(f16)xpA0.y; v[2]=(f16)xpA0.z; v[3]=(f16)xpA0.w;
                     v[4]=(f16)xpA1.x; v[5]=(f16)xpA1.y; v[6]=(f16)xpA1.z; v[7]=(f16)xpA1.w;
            *(f16x8*)(sx + xrow * SXS + xseg * 8) = v;
        }
        bar_lds();

        f16x8 ya[5];
        #pragma unroll
        for (int kt = 0; kt < 5; ++kt)
            ya[kt] = *(const f16x8*)(sy0 + ln * SYS + kt * 32 + kg * 8);
        f32x4 a1 = {0,0,0,0};
        #pragma unroll
        for (int kt = 0; kt < 5; ++kt) a1 = MFMA16(ya[kt], w1f[kt], a1);
        #pragma unroll
        for (int j = 0; j < 4; ++j)
            sy1[(4 * kg + j) * SYS + col] = (f16)fmaxf(a1[j] + b3, 0.f);
        if (w == 1) {
            f32x4 a8 = {0,0,0,0};
            #pragma unroll
            for (int kt = 0; kt < 5; ++kt) a8 = MFMA16(ya[kt], ext[kt], a8);
            #pragma unroll
            for (int j = 0; j < 4; ++j)
                sy1[(4 * kg + j) * SYS + 128 + ln] = (f16)fmaxf(a8[j] + bext, 0.f);
        }
        #pragma unroll
        for (int j = 0; j < 4; ++j)
            sz[(4 * kg + j) * SZS + col] = sigm(pzv[j] + b1z);
        f16x8 xa[4];
        #pragma unroll
        for (int kt = 0; kt < 4; ++kt)
            xa[kt] = *(const f16x8*)(sx + ln * SXS + kt * 32 + kg * 8);
        {
            f32x4 a = {0,0,0,0};
            #pragma unroll
            for (int kt = 0; kt < 4; ++kt) a = MFMA16(xa[kt], wrx[kt], a);
            *(f32x4*)(pg + (unsigned)col * PGS + kg * 4) = a;
            f32x4 b = {0,0,0,0};
            #pragma unroll
            for (int kt = 0; kt < 4; ++kt) b = MFMA16(xa[kt], wzx[kt], b);
            *(f32x4*)(pg + (unsigned)(128 + col) * PGS + kg * 4) = b;
        }
        bar_lds();

        f16x8 za[5];
        #pragma unroll
        for (int kt = 0; kt < 5; ++kt)
            za[kt] = *(const f16x8*)(sy1 + ln * SYS + kt * 32 + kg * 8);
        f32x4 a2 = {0,0,0,0};
        #pragma unroll
        for (int kt = 0; kt < 5; ++kt) a2 = MFMA16(za[kt], w2f[kt], a2);
        {
            f32x4 a = {0,0,0,0};
            #pragma unroll
            for (int kt = 0; kt < 4; ++kt) a = MFMA16(xa[kt], w0x[kt], a);
            *(f32x4*)(pm + (unsigned)col * PGS + kg * 4) = a;
            if (w == 2) {
                f32x4 d = {0,0,0,0};
                #pragma unroll
                for (int kt = 0; kt < 4; ++kt) d = MFMA16(xa[kt], ext[kt], d);
                *(f32x4*)(pm + (unsigned)(128 + ln) * PGS + kg * 4) = d;
            }
        }
        #pragma unroll
        for (int j = 0; j < 4; ++j) {
            const int m = 4 * kg + j;
            const float ht = tanh_fast(a2[j] + b4);
            const float zz = sz[m * SZS + col];
            const float hn = (1.f - zz) * shf[m * SZS + col] + zz * ht;
            shf[m * SZS + col] = hn;
            sh16[m * SXS + col] = (f16)hn;
            *op[j] = hn; op[j] += DH;
        }
        bar_lds();
        xpA0 = xpB0; xpA1 = xpB1;
    }

    for (int i = tid; i < MR * DH; i += 512)
        hid_out[(size_t)(b0 + (i >> 7)) * DH + (i & 127)] = shf[(i >> 7) * SZS + (i & 127)];
}

extern "C" void kernel_launch(void* const* d_in, const int* in_sizes, int n_in,
                              void* d_out, int out_size, void* d_ws, size_t ws_size,
                              hipStream_t stream) {
    const float* inputs = (const float*)d_in[0];
    const float* r_w  = (const float*)d_in[1];
    const float* r_b  = (const float*)d_in[2];
    const float* z_w  = (const float*)d_in[3];
    const float* z_b  = (const float*)d_in[4];
    const float* h_w0 = (const float*)d_in[5];
    const float* h_b0 = (const float*)d_in[6];
    const float* h_w1 = (const float*)d_in[7];
    const float* h_b1 = (const float*)d_in[8];
    const float* h_w2 = (const float*)d_in[9];
    const float* h_b2 = (const float*)d_in[10];

    float* out = (float*)d_out;
    float* hid = out + (size_t)BATCH * SEQ * DH;

    if (ws_size >= WS_ELEMS * sizeof(f16)) {
        f16* ws = (f16*)d_ws;
        hipLaunchKernelGGL(xproj_kernel, dim3(16 * 32), dim3(512), 0, stream,
                           inputs, r_w, z_w, h_w0, ws);
        hipLaunchKernelGGL(hgru_kernel, dim3(BATCH / MR), dim3(512), 0, stream,
                           ws, r_w, r_b, z_w, z_b,
                           h_w0, h_b0, h_w1, h_b1, h_w2, h_b2,
                           out, hid);
    } else {
        hipLaunchKernelGGL(hgru_fallback, dim3(BATCH / MR), dim3(512), 0, stream,
                           inputs, r_w, r_b, z_w, z_b,
                           h_w0, h_b0, h_w1, h_b1, h_w2, h_b2,
                           out, hid);
    }
}